// Round 1
// baseline (202.567 us; speedup 1.0000x reference)
//
#include <hip/hip_runtime.h>

typedef unsigned short u16;
typedef unsigned int u32;
typedef __attribute__((ext_vector_type(8))) short bf16x8;
typedef __attribute__((ext_vector_type(4))) float f32x4;
typedef __attribute__((ext_vector_type(4))) u32 u32x4;
typedef __attribute__((ext_vector_type(2))) u32 u32x2;

__device__ __forceinline__ u16 f2bf(float f) {
  u32 u = __builtin_bit_cast(u32, f);
  return (u16)((u + 0x7FFFu + ((u >> 16) & 1u)) >> 16);
}
__device__ __forceinline__ float bf2f(u16 b) {
  return __builtin_bit_cast(float, (u32)b << 16);
}

__device__ __forceinline__ void lds_async16(const void* g, void* l) {
  auto gp = reinterpret_cast<const __attribute__((address_space(1))) u32*>(
      reinterpret_cast<uintptr_t>(g));
  auto lp = reinterpret_cast<__attribute__((address_space(3))) u32*>(
      reinterpret_cast<uintptr_t>(l));
  __builtin_amdgcn_global_load_lds(gp, lp, 16, 0, 0);
}

// ---------------- fp32 -> bf16 convert (vec4) ----------------
__global__ void cvt_kernel(const float* __restrict__ in, u16* __restrict__ out, int n4) {
  int i = blockIdx.x * 256 + threadIdx.x;
  if (i < n4) {
    f32x4 v = *(const f32x4*)(in + (size_t)i * 4);
    u32x2 o;
    o[0] = (u32)f2bf(v[0]) | ((u32)f2bf(v[1]) << 16);
    o[1] = (u32)f2bf(v[2]) | ((u32)f2bf(v[3]) << 16);
    *(u32x2*)(out + (size_t)i * 4) = o;
  }
}

// ---------------- GEMM: C[m][n] = sum_k A[m][k]*B[n][k] + bias[n] ----------------
// A: M x K bf16 row-major, B: N x K bf16 row-major. 128x128 tile, BK=32, m97 structure.
template <bool OUT_BF16>
__global__ __launch_bounds__(256) void gemm_bt_kernel(
    const u16* __restrict__ A, const u16* __restrict__ B,
    const float* __restrict__ bias, void* __restrict__ C,
    int M, int N, int K) {
  __shared__ u16 sA[128 * 32];
  __shared__ u16 sB[128 * 32];
  const int tid = threadIdx.x;
  const int m0 = blockIdx.x * 128;
  const int n0 = blockIdx.y * 128;
  const int w = tid >> 6;
  const int lane = tid & 63;
  const int wr = (w >> 1) * 64;
  const int wc = (w & 1) * 64;
  const int lm = lane & 15;
  const int lk = (lane >> 4) * 8;

  f32x4 acc[4][4] = {};

  const int srow = tid >> 2;
  const int ssub = (tid & 3) * 8;
  const u16* Ag = A + (size_t)(m0 + srow) * K + ssub;
  const u16* Bg = B + (size_t)(n0 + srow) * K + ssub;
  const size_t rstep = (size_t)64 * K;

  for (int k0 = 0; k0 < K; k0 += 32) {
    __syncthreads();
    lds_async16(Ag + k0, &sA[tid * 8]);
    lds_async16(Ag + rstep + k0, &sA[2048 + tid * 8]);
    lds_async16(Bg + k0, &sB[tid * 8]);
    lds_async16(Bg + rstep + k0, &sB[2048 + tid * 8]);
    __syncthreads();
    bf16x8 af[4], bfr[4];
#pragma unroll
    for (int i = 0; i < 4; ++i)
      af[i] = *(const bf16x8*)&sA[(wr + i * 16 + lm) * 32 + lk];
#pragma unroll
    for (int j = 0; j < 4; ++j)
      bfr[j] = *(const bf16x8*)&sB[(wc + j * 16 + lm) * 32 + lk];
#pragma unroll
    for (int i = 0; i < 4; ++i)
#pragma unroll
      for (int j = 0; j < 4; ++j)
        acc[i][j] = __builtin_amdgcn_mfma_f32_16x16x32_bf16(af[i], bfr[j], acc[i][j], 0, 0, 0);
  }

  const int r0 = (lane >> 4) * 4;
#pragma unroll
  for (int j = 0; j < 4; ++j) {
    const int n = n0 + wc + j * 16 + lm;
    const float bv = bias[n];
#pragma unroll
    for (int i = 0; i < 4; ++i) {
#pragma unroll
      for (int r = 0; r < 4; ++r) {
        const int m = m0 + wr + i * 16 + r0 + r;
        float v = acc[i][j][r] + bv;
        if (OUT_BF16)
          ((u16*)C)[(size_t)m * N + n] = f2bf(v);
        else
          ((float*)C)[(size_t)m * N + n] = v;
      }
    }
  }
}

// ---------------- fused per-(block,head) attention ----------------
// qkv: 33792 x 768 bf16 (q|k|v each 256 cols). o_ws: (256 blocks x 256 rows x 256 f) bf16.
__global__ __launch_bounds__(256, 2) void attn_kernel(const u16* __restrict__ qkv,
                                                      u16* __restrict__ o_ws) {
  __shared__ u16 sK[256 * 40];    // row stride 40 u16 = 80B: 16B aligned, ~2-way banks
  __shared__ u16 sVt[32 * 264];   // V transposed, stride 264 u16 = 528B
  __shared__ u16 sP[4 * 64 * 72]; // per-wave P tile, stride 72 u16 = 144B

  const int bid = blockIdx.x;
  const int n = bid >> 3;
  const int h = bid & 7;
  const int rowbase = (n >> 5) * 4224 + (n & 31) * 128;
  const int tid = threadIdx.x;
  const int w = tid >> 6;
  const int lane = tid & 63;
  const int lm = lane & 15;
  const int lg = lane >> 4;

  // stage K (row-major) and V (transposed) for this head
#pragma unroll
  for (int it = 0; it < 4; ++it) {
    int c = it * 256 + tid;
    int row = c >> 2;
    int sub = (c & 3) * 8;
    const u16* gk = qkv + (size_t)(rowbase + row) * 768 + 256 + h * 32 + sub;
    *(u32x4*)&sK[row * 40 + sub] = *(const u32x4*)gk;
    const u16* gv = qkv + (size_t)(rowbase + row) * 768 + 512 + h * 32 + sub;
    u32x4 vv = *(const u32x4*)gv;
#pragma unroll
    for (int q = 0; q < 4; ++q) {
      sVt[(sub + 2 * q) * 264 + row] = (u16)(vv[q] & 0xFFFFu);
      sVt[(sub + 2 * q + 1) * 264 + row] = (u16)(vv[q] >> 16);
    }
  }

  // Q fragments straight from global (wave-private rows)
  bf16x8 qf[4];
#pragma unroll
  for (int rt = 0; rt < 4; ++rt) {
    int row = rowbase + w * 64 + rt * 16 + lm;
    qf[rt] = *(const bf16x8*)(qkv + (size_t)row * 768 + h * 32 + lg * 8);
  }

  __syncthreads();

  f32x4 oacc[4][2] = {};
  float lsum[4][4] = {};
  u16* myP = sP + w * (64 * 72);
  const float scale = 0.17677669529663687f;

  for (int ch = 0; ch < 4; ++ch) {
    // S = Q * Kc^T  (one 16x16x32 MFMA covers dh=32)
    bf16x8 kf[4];
#pragma unroll
    for (int ct = 0; ct < 4; ++ct)
      kf[ct] = *(const bf16x8*)&sK[(ch * 64 + ct * 16 + lm) * 40 + lg * 8];
    f32x4 s[4][4] = {};
#pragma unroll
    for (int rt = 0; rt < 4; ++rt)
#pragma unroll
      for (int ct = 0; ct < 4; ++ct)
        s[rt][ct] = __builtin_amdgcn_mfma_f32_16x16x32_bf16(qf[rt], kf[ct], s[rt][ct], 0, 0, 0);

    // P = exp(S*scale + band), accumulate row sums, stash P (bf16) in LDS
#pragma unroll
    for (int rt = 0; rt < 4; ++rt)
#pragma unroll
      for (int ct = 0; ct < 4; ++ct) {
        int j = ch * 64 + ct * 16 + lm;
#pragma unroll
        for (int r = 0; r < 4; ++r) {
          int i = w * 64 + rt * 16 + lg * 4 + r;
          int di = i - j;
          float sv = s[rt][ct][r] * scale + ((di >= 0 && di < 128) ? 1.0f : 0.0f);
          float p = __expf(sv);
          lsum[rt][r] += p;
          myP[(rt * 16 + lg * 4 + r) * 72 + ct * 16 + lm] = f2bf(p);
        }
      }

    // O += P * Vc (wave-private P: in-order LDS, no barrier needed)
#pragma unroll
    for (int kt = 0; kt < 2; ++kt) {
      bf16x8 pf[4], vf[2];
#pragma unroll
      for (int rt = 0; rt < 4; ++rt)
        pf[rt] = *(const bf16x8*)&myP[(rt * 16 + lm) * 72 + kt * 32 + lg * 8];
#pragma unroll
      for (int ct = 0; ct < 2; ++ct)
        vf[ct] = *(const bf16x8*)&sVt[(ct * 16 + lm) * 264 + ch * 64 + kt * 32 + lg * 8];
#pragma unroll
      for (int rt = 0; rt < 4; ++rt)
#pragma unroll
        for (int ct = 0; ct < 2; ++ct)
          oacc[rt][ct] = __builtin_amdgcn_mfma_f32_16x16x32_bf16(pf[rt], vf[ct], oacc[rt][ct], 0, 0, 0);
    }
  }

  // softmax denominators: reduce across the 16 lanes holding each row
#pragma unroll
  for (int rt = 0; rt < 4; ++rt)
#pragma unroll
    for (int r = 0; r < 4; ++r) {
      float v = lsum[rt][r];
      v += __shfl_xor(v, 1);
      v += __shfl_xor(v, 2);
      v += __shfl_xor(v, 4);
      v += __shfl_xor(v, 8);
      lsum[rt][r] = 1.0f / v;
    }

#pragma unroll
  for (int rt = 0; rt < 4; ++rt)
#pragma unroll
    for (int ct = 0; ct < 2; ++ct)
#pragma unroll
      for (int r = 0; r < 4; ++r) {
        int i = w * 64 + rt * 16 + lg * 4 + r;
        int d = ct * 16 + lm;
        float v = oacc[rt][ct][r] * lsum[rt][r];
        o_ws[((size_t)(n * 256 + i)) * 256 + h * 32 + d] = f2bf(v);
      }
}

// ---------------- overlap-add combine: oc[t] = sum(covering o_ws)/cnt ----------------
__global__ void combine_kernel(const u16* __restrict__ o_ws, u16* __restrict__ oc) {
  int gid = blockIdx.x * 256 + threadIdx.x;
  int m = gid >> 5;             // global row (bc*4224 + t)
  int f0 = (gid & 31) << 3;     // 8 features per thread
  int bc = m / 4224;
  int t = m - bc * 4224;
  int i0 = t >> 7;
  float a[8] = {0.f, 0.f, 0.f, 0.f, 0.f, 0.f, 0.f, 0.f};
  if (i0 <= 31) {
    const u16* p = o_ws + ((size_t)((bc * 32 + i0) * 256 + (t - (i0 << 7)))) * 256 + f0;
    u32x4 v = *(const u32x4*)p;
#pragma unroll
    for (int q = 0; q < 4; ++q) {
      a[2 * q] += bf2f((u16)(v[q] & 0xFFFFu));
      a[2 * q + 1] += bf2f((u16)(v[q] >> 16));
    }
  }
  if (i0 >= 1) {
    int i1 = i0 - 1;
    const u16* p = o_ws + ((size_t)((bc * 32 + i1) * 256 + (t - (i1 << 7)))) * 256 + f0;
    u32x4 v = *(const u32x4*)p;
#pragma unroll
    for (int q = 0; q < 4; ++q) {
      a[2 * q] += bf2f((u16)(v[q] & 0xFFFFu));
      a[2 * q + 1] += bf2f((u16)(v[q] >> 16));
    }
  }
  float sc = (i0 >= 1 && i0 <= 31) ? 0.5f : 1.0f;
  u32x2 o;
  o[0] = (u32)f2bf(a[0] * sc) | ((u32)f2bf(a[1] * sc) << 16);
  o[1] = (u32)f2bf(a[2] * sc) | ((u32)f2bf(a[3] * sc) << 16);
  u32x2 o2;
  o2[0] = (u32)f2bf(a[4] * sc) | ((u32)f2bf(a[5] * sc) << 16);
  o2[1] = (u32)f2bf(a[6] * sc) | ((u32)f2bf(a[7] * sc) << 16);
  u16* dst = oc + (size_t)m * 256 + f0;
  *(u32x2*)dst = o;
  *(u32x2*)(dst + 4) = o2;
}

extern "C" void kernel_launch(void* const* d_in, const int* in_sizes, int n_in,
                              void* d_out, int out_size, void* d_ws, size_t ws_size,
                              hipStream_t stream) {
  const float* x = (const float*)d_in[0];
  const float* w_in = (const float*)d_in[1];
  const float* b_in = (const float*)d_in[2];
  const float* w_out = (const float*)d_in[3];
  const float* b_out = (const float*)d_in[4];
  float* y = (float*)d_out;
  char* ws = (char*)d_ws;

  // workspace layout (bytes)
  u16* qkv = (u16*)(ws);                   // 33792*768*2   = 51,904,512
  u16* xbf = (u16*)(ws + 51904512);        // 33792*256*2   = 17,301,504 (reused as oc)
  u16* ows = (u16*)(ws + 69206016);        // 256*256*256*2 = 33,554,432
  u16* winb = (u16*)(ws + 102760448);      // 768*256*2     = 393,216
  u16* woutb = (u16*)(ws + 103153664);     // 256*256*2     = 131,072  (end 103,284,736)

  cvt_kernel<<<8448, 256, 0, stream>>>(x, xbf, 2162688);
  cvt_kernel<<<192, 256, 0, stream>>>(w_in, winb, 49152);
  cvt_kernel<<<64, 256, 0, stream>>>(w_out, woutb, 16384);

  // qkv = x @ w_in^T + b_in  (once per row; overlapping blocks share rows)
  gemm_bt_kernel<true><<<dim3(264, 6), 256, 0, stream>>>(xbf, winb, b_in, qkv, 33792, 768, 256);

  // per-(block, head) attention
  attn_kernel<<<2048, 256, 0, stream>>>(qkv, ows);

  // overlap-add + count division (commutes with the linear w_out projection)
  combine_kernel<<<4224, 256, 0, stream>>>(ows, xbf);

  // y = oc @ w_out^T + b_out
  gemm_bt_kernel<false><<<dim3(264, 2), 256, 0, stream>>>(xbf, woutb, b_out, y, 33792, 256, 256);
}